// Round 7
// baseline (141.223 us; speedup 1.0000x reference)
//
#include <hip/hip_runtime.h>
#include <hip/hip_fp16.h>
#include <cstdint>
#include <cstddef>

// z = soft_thresh(Toeplitz(v) @ x + W2 @ y, beta) -- complex, N=1024, M=256, B=1024
// Output = Re(z) only: [1024,1024] f32.
//
// R25: ALGORITHMIC pivot. Toeplitz(v)@x is a linear convolution -> computed
// exactly via length-2048 circular FFT convolution per column (fp32, LDS-
// resident, DIF fwd -> pointwise in bit-reversed domain -> DIT inv, no bit
// reversal pass). Only W2@y remains as a GEMM: K=512 embedded (vs 2560),
// reusing the R13 64x64/256thr/2blk-CU/2-deep structure verbatim with NIT=4.
// Chain: build_all (A2,B2t,xT,V) -> gemm_w2y -> fft_conv -> combine.
// R13-structure ledger: R19 +9, R21 +1, R22 +0, R23 +7, R24 +8 => structure
// is a sharp local optimum; only work-reduction of K remains.

#define BETA_F 0.01f
#define EPS_F  1e-12f

typedef __attribute__((ext_vector_type(8))) _Float16 half8;
typedef __attribute__((ext_vector_type(4))) _Float16 half4;
typedef __attribute__((ext_vector_type(4))) float   floatx4;

__device__ alignas(16) _Float16 g_A2[1024 * 512];        // 1 MB  [W2_re | W2_im]
__device__ alignas(16) _Float16 g_B2t[2048 * 512];       // 2 MB  [y embedding]^T
__device__ alignas(16) float2   g_xT[1024 * 1024];       // 8 MB  xT[b][n]
__device__ alignas(16) float2   g_V[2048];               // FFT(u~)/2048, bitrev order
__device__ alignas(16) float2   g_convT[1024 * 1024];    // 8 MB  conv^T[b][i]
__device__ alignas(16) float2   g_w2y[1024 * 1024];      // 8 MB  (W2 y)[i][n]

// ---------------- prep: A2', B2t, xT, V --------------------------------------
__global__ __launch_bounds__(256) void build_all(
    const float* __restrict__ v_re, const float* __restrict__ v_im,
    const float* __restrict__ W2_re, const float* __restrict__ W2_im,
    const float* __restrict__ x_re, const float* __restrict__ x_im,
    const float* __restrict__ y_re, const float* __restrict__ y_im)
{
    __shared__ __align__(16) char sbuf[24576];
    const int bx  = blockIdx.x;
    const int tid = threadIdx.x;

    if (bx < 256) {                            // ---- A2'[1024][512] fp16
        int t  = bx * 256 + tid;               // 64K threads x 8 elems
        int i  = t >> 6;
        int kp = (t & 63) * 8;                 // 0..504, 8-chunks don't straddle 256
        half8 h;
        if (kp < 256) {
            const float* s = W2_re + i * 256 + kp;
#pragma unroll
            for (int j = 0; j < 8; ++j) h[j] = (_Float16)s[j];
        } else {
            const float* s = W2_im + i * 256 + (kp - 256);
#pragma unroll
            for (int j = 0; j < 8; ++j) h[j] = (_Float16)s[j];
        }
        *reinterpret_cast<half8*>(g_A2 + (size_t)i * 512 + kp) = h;
        return;
    }
    if (bx < 512) {                            // ---- B2t[2048][512] fp16 (y^T)
        float (*lre)[33] = (float(*)[33])sbuf;
        float (*lim)[33] = (float(*)[33])(sbuf + 4224);
        int idx = bx - 256;                    // 0..255
        int bk  = idx & 7;                     // k-tile (y rows 0..255)
        int by  = idx >> 3;                    // n-tile
        int k0  = bk * 32;
        int n0  = by * 32;
        {
            int kk  = tid >> 3;
            int tx4 = (tid & 7) * 4;
            const floatx4 re4 = *reinterpret_cast<const floatx4*>(
                y_re + (size_t)(k0 + kk) * 1024 + n0 + tx4);
            const floatx4 im4 = *reinterpret_cast<const floatx4*>(
                y_im + (size_t)(k0 + kk) * 1024 + n0 + tx4);
#pragma unroll
            for (int j = 0; j < 4; ++j) {
                lre[kk][tx4 + j] = re4[j];
                lim[kk][tx4 + j] = im4[j];
            }
        }
        __syncthreads();
        int lane_n = tid >> 3;
        int kq     = (tid & 7) * 4;
        half4 hre, him, hmim;
#pragma unroll
        for (int j = 0; j < 4; ++j) {
            float re = lre[kq + j][lane_n];
            float im = lim[kq + j][lane_n];
            hre[j]  = (_Float16)re;
            him[j]  = (_Float16)im;
            hmim[j] = (_Float16)(-im);
        }
        int n = n0 + lane_n;
        _Float16* r0 = g_B2t + (size_t)(2 * n)     * 512;
        _Float16* r1 = g_B2t + (size_t)(2 * n + 1) * 512;
        *reinterpret_cast<half4*>(r0 + k0 + kq)       = hre;   // [y_re ; -y_im]
        *reinterpret_cast<half4*>(r0 + 256 + k0 + kq) = hmim;
        *reinterpret_cast<half4*>(r1 + k0 + kq)       = him;   // [y_im ;  y_re]
        *reinterpret_cast<half4*>(r1 + 256 + k0 + kq) = hre;
        return;
    }
    if (bx < 1536) {                           // ---- xT[b][n] float2 (x^T)
        float (*lre)[33] = (float(*)[33])sbuf;
        float (*lim)[33] = (float(*)[33])(sbuf + 4224);
        int idx = bx - 512;                    // 0..1023
        int n0  = (idx >> 5) * 32;             // x row tile
        int b0  = (idx & 31) * 32;             // x col tile
        {
            int kk  = tid >> 3;
            int tx4 = (tid & 7) * 4;
            const floatx4 re4 = *reinterpret_cast<const floatx4*>(
                x_re + (size_t)(n0 + kk) * 1024 + b0 + tx4);
            const floatx4 im4 = *reinterpret_cast<const floatx4*>(
                x_im + (size_t)(n0 + kk) * 1024 + b0 + tx4);
#pragma unroll
            for (int j = 0; j < 4; ++j) {
                lre[kk][tx4 + j] = re4[j];
                lim[kk][tx4 + j] = im4[j];
            }
        }
        __syncthreads();
        int bb  = tid >> 3;                    // xT row (b)
        int nn4 = (tid & 7) * 4;               // 4 consecutive n
        float2* dst = g_xT + (size_t)(b0 + bb) * 1024 + n0 + nn4;
        floatx4 w0, w1;
        w0[0] = lre[nn4 + 0][bb]; w0[1] = lim[nn4 + 0][bb];
        w0[2] = lre[nn4 + 1][bb]; w0[3] = lim[nn4 + 1][bb];
        w1[0] = lre[nn4 + 2][bb]; w1[1] = lim[nn4 + 2][bb];
        w1[2] = lre[nn4 + 3][bb]; w1[3] = lim[nn4 + 3][bb];
        *reinterpret_cast<floatx4*>(dst)     = w0;
        *reinterpret_cast<floatx4*>(dst + 2) = w1;
        return;
    }
    // ---- bx == 1536: V = DIF-FFT_2048(u~) * (1/2048), bit-reversed order ----
    float2* du = (float2*)sbuf;                // 2048 x 8B = 16KB
    float*  twr = (float*)(sbuf + 16384);      // 4KB
    float*  twi = (float*)(sbuf + 20480);      // 4KB
#pragma unroll
    for (int r = 0; r < 4; ++r) {              // twiddle: tw[k] = exp(-2pi i k/2048)
        int k = tid + 256 * r;
        float ang = (float)k * 3.0679615757712823e-3f;   // 2pi/2048
        float s, c;
        __sincosf(ang, &s, &c);
        twr[k] = c; twi[k] = -s;
    }
#pragma unroll
    for (int r = 0; r < 8; ++r) {              // u~[k]
        int k = tid + 256 * r;
        float2 val;
        if (k < 1024)      { val.x = v_re[1023 + k]; val.y = v_im[1023 + k]; }
        else if (k == 1024){ val.x = 0.f; val.y = 0.f; }
        else               { val.x = v_re[k - 1025]; val.y = v_im[k - 1025]; }
        du[k] = val;
    }
    for (int s = 0; s < 11; ++s) {             // DIF forward
        int lh = 10 - s, h = 1 << lh;
        __syncthreads();
#pragma unroll
        for (int r = 0; r < 4; ++r) {
            int i  = tid + 256 * r;
            int j  = i & (h - 1);
            int i0 = ((i >> lh) << (lh + 1)) | j;
            int i1 = i0 + h;
            float2 a = du[i0], b = du[i1];
            float dx = a.x - b.x, dy = a.y - b.y;
            int ti = j << s;
            float wr = twr[ti], wi = twi[ti];
            float2 s0; s0.x = a.x + b.x; s0.y = a.y + b.y;
            float2 d0; d0.x = dx * wr - dy * wi; d0.y = dx * wi + dy * wr;
            du[i0] = s0; du[i1] = d0;
        }
    }
    __syncthreads();
#pragma unroll
    for (int r = 0; r < 8; ++r) {
        int k = tid + 256 * r;
        float2 v = du[k];
        v.x *= (1.0f / 2048.0f); v.y *= (1.0f / 2048.0f);
        g_V[k] = v;
    }
}

// ---------------- W2@y GEMM (real embedding, K=512) + w2y store --------------
// R13 structure: 512 blocks (2/CU), 256 thr (4 waves 2x2), 64x64 tile, BK=128,
// NIT=4, dbuf LDS 64KB, 2-deep reg prefetch, XOR swizzle, 1 barrier/iter.
__global__ __launch_bounds__(256, 2) void gemm_w2y()
{
    __shared__ __align__(16) _Float16 As[2 * 4 * 64 * 32];
    __shared__ __align__(16) _Float16 Bs[2 * 4 * 64 * 32];

    const int tid  = threadIdx.x;
    const int lane = tid & 63;
    const int w    = tid >> 6;
    const int wm   = w >> 1;
    const int wn   = w & 1;

    const int bid = blockIdx.x;
    const int xcd = bid & 7;
    const int t   = bid >> 3;
    const int mi0 = ((xcd & 1) * 8 + (t & 7)) * 64;
    const int ni0 = ((xcd >> 1) * 8 + (t >> 3)) * 64;

    floatx4 acc[2][2];
#pragma unroll
    for (int a = 0; a < 2; ++a)
#pragma unroll
        for (int b = 0; b < 2; ++b) acc[a][b] = (floatx4)0.0f;

    const int rS = tid >> 2;
    const int jS = tid & 3;
    const int s0 = ((rS & 15) >> 1) & 3;
    char* asW = (char*)As + rS * 64 + ((jS ^ s0) * 16);
    char* bsW = (char*)Bs + rS * 64 + ((jS ^ s0) * 16);
    const _Float16* gA = g_A2  + (size_t)(mi0 + rS) * 512 + jS * 8;
    const _Float16* gB = g_B2t + (size_t)(ni0 + rS) * 512 + jS * 8;

    const int rowA = lane & 15;
    const int q    = lane >> 4;
    const int coff = (q ^ ((rowA >> 1) & 3)) * 16;

    const int NIT = 512 / 128;           // 4

    half8 sA[2][4], sB[2][4];
    {
        half8 tA[4], tB[4];
#pragma unroll
        for (int ks = 0; ks < 4; ++ks) {
            tA[ks] = *reinterpret_cast<const half8*>(gA + ks * 32);
            tB[ks] = *reinterpret_cast<const half8*>(gB + ks * 32);
        }
#pragma unroll
        for (int ks = 0; ks < 4; ++ks) {
            sA[1][ks] = *reinterpret_cast<const half8*>(gA + 128 + ks * 32);
            sB[1][ks] = *reinterpret_cast<const half8*>(gB + 128 + ks * 32);
        }
#pragma unroll
        for (int ks = 0; ks < 4; ++ks) {
            *reinterpret_cast<half8*>(asW + ks * 4096) = tA[ks];
            *reinterpret_cast<half8*>(bsW + ks * 4096) = tB[ks];
        }
    }
    __syncthreads();

#pragma unroll 2
    for (int kt = 0; kt < NIT; ++kt) {
        const int cur = kt & 1;
        const int nxt = cur ^ 1;
        if (kt + 2 < NIT) {
            const _Float16* ga = gA + (size_t)(kt + 2) * 128;
            const _Float16* gb = gB + (size_t)(kt + 2) * 128;
#pragma unroll
            for (int ks = 0; ks < 4; ++ks) {
                sA[cur][ks] = *reinterpret_cast<const half8*>(ga + ks * 32);
                sB[cur][ks] = *reinterpret_cast<const half8*>(gb + ks * 32);
            }
        }
        const char* Ab = (const char*)As + cur * 16384;
        const char* Bb = (const char*)Bs + cur * 16384;
#pragma unroll
        for (int ks = 0; ks < 4; ++ks) {
            half8 af[2], bf[2];
#pragma unroll
            for (int mi = 0; mi < 2; ++mi) {
                int r = wm * 32 + mi * 16 + rowA;
                af[mi] = *reinterpret_cast<const half8*>(Ab + ks * 4096 + r * 64 + coff);
            }
#pragma unroll
            for (int ni = 0; ni < 2; ++ni) {
                int r = wn * 32 + ni * 16 + rowA;
                bf[ni] = *reinterpret_cast<const half8*>(Bb + ks * 4096 + r * 64 + coff);
            }
#pragma unroll
            for (int mi = 0; mi < 2; ++mi)
#pragma unroll
                for (int ni = 0; ni < 2; ++ni)
                    acc[mi][ni] = __builtin_amdgcn_mfma_f32_16x16x32_f16(
                        af[mi], bf[ni], acc[mi][ni], 0, 0, 0);
        }
        if (kt + 1 < NIT) {
            char* aw = asW + nxt * 16384;
            char* bw = bsW + nxt * 16384;
#pragma unroll
            for (int ks = 0; ks < 4; ++ks) {
                *reinterpret_cast<half8*>(aw + ks * 4096) = sA[nxt][ks];
                *reinterpret_cast<half8*>(bw + ks * 4096) = sB[nxt][ks];
            }
        }
        __syncthreads();
    }

    // epilogue: even C'-col lane holds Re, lane^1 holds Im -> w2y[row][n] float2
    const int colL  = lane & 15;
    const int rquad = (lane >> 4) * 4;
#pragma unroll
    for (int mi = 0; mi < 2; ++mi)
#pragma unroll
        for (int ni = 0; ni < 2; ++ni)
#pragma unroll
            for (int r = 0; r < 4; ++r) {
                float c = acc[mi][ni][r];
                float p = __shfl_xor(c, 1, 64);
                if (!(colL & 1)) {
                    int row = mi0 + wm * 32 + mi * 16 + rquad + r;
                    int col = ni0 + wn * 32 + ni * 16 + colL;
                    float2 v; v.x = c; v.y = p;
                    g_w2y[(size_t)row * 1024 + (col >> 1)] = v;
                }
            }
}

// ---------------- FFT convolution: convT[b][i] = (Toeplitz(v)@x)[i][b] -------
// 512 blocks x 256 thr, 2 columns/block. LDS: dat[2][2048] f2 (32KB) + tw (8KB).
// DIF fwd (nat->bitrev) -> pointwise * V (bitrev) -> DIT inv (bitrev->nat).
__global__ __launch_bounds__(256, 2) void fft_conv()
{
    __shared__ float2 dat[2][2048];
    __shared__ float  twr[1024];
    __shared__ float  twi[1024];

    const int tid = threadIdx.x;
    const int c   = tid >> 7;            // which FFT (column)
    const int tl  = tid & 127;
    const int b0  = blockIdx.x * 2;

#pragma unroll
    for (int r = 0; r < 4; ++r) {
        int k = tid + 256 * r;
        float ang = (float)k * 3.0679615757712823e-3f;
        float s, cc;
        __sincosf(ang, &s, &cc);
        twr[k] = cc; twi[k] = -s;
    }
    const float2* src = g_xT + (size_t)(b0 + c) * 1024;
#pragma unroll
    for (int r = 0; r < 8; ++r) {
        int n = tl + 128 * r;
        dat[c][n] = src[n];
    }
#pragma unroll
    for (int r = 8; r < 16; ++r) {
        int n = tl + 128 * r;
        float2 z; z.x = 0.f; z.y = 0.f;
        dat[c][n] = z;
    }

    for (int s = 0; s < 11; ++s) {       // forward DIF
        int lh = 10 - s, h = 1 << lh;
        __syncthreads();
#pragma unroll
        for (int r = 0; r < 8; ++r) {
            int i  = tl + 128 * r;
            int j  = i & (h - 1);
            int i0 = ((i >> lh) << (lh + 1)) | j;
            int i1 = i0 + h;
            float2 a = dat[c][i0], b = dat[c][i1];
            float dx = a.x - b.x, dy = a.y - b.y;
            int ti = j << s;
            float wr = twr[ti], wi = twi[ti];
            float2 s0; s0.x = a.x + b.x; s0.y = a.y + b.y;
            float2 d0; d0.x = dx * wr - dy * wi; d0.y = dx * wi + dy * wr;
            dat[c][i0] = s0; dat[c][i1] = d0;
        }
    }
    __syncthreads();
#pragma unroll
    for (int r = 0; r < 16; ++r) {       // pointwise (bitrev domain), V pre-scaled
        int k = tl + 128 * r;
        float2 a = dat[c][k], v = g_V[k];
        float2 m; m.x = a.x * v.x - a.y * v.y; m.y = a.x * v.y + a.y * v.x;
        dat[c][k] = m;
    }
    for (int ss = 0; ss < 11; ++ss) {    // inverse DIT (conj twiddles)
        int h = 1 << ss;
        __syncthreads();
#pragma unroll
        for (int r = 0; r < 8; ++r) {
            int i  = tl + 128 * r;
            int j  = i & (h - 1);
            int i0 = ((i >> ss) << (ss + 1)) | j;
            int i1 = i0 + h;
            int ti = j << (10 - ss);
            float wr = twr[ti], wi = twi[ti];
            float2 a = dat[c][i0], b = dat[c][i1];
            float2 bt; bt.x = b.x * wr + b.y * wi; bt.y = b.y * wr - b.x * wi;
            float2 p0; p0.x = a.x + bt.x; p0.y = a.y + bt.y;
            float2 p1; p1.x = a.x - bt.x; p1.y = a.y - bt.y;
            dat[c][i0] = p0; dat[c][i1] = p1;
        }
    }
    __syncthreads();
    float2* dst = g_convT + (size_t)(b0 + c) * 1024;
#pragma unroll
    for (int r = 0; r < 8; ++r) {
        int n = tl + 128 * r;
        dst[n] = dat[c][n];
    }
}

// ---------------- combine: out[i][b] = softthresh(conv + w2y).re -------------
// 1024 blocks, 256 thr, 32x32 tiles; convT transposed through LDS.
__global__ __launch_bounds__(256) void combine(float* __restrict__ out, int out_n)
{
    __shared__ float2 cvl[32][33];
    const int tid = threadIdx.x;
    const int bx  = blockIdx.x;
    const int i0  = (bx >> 5) * 32;
    const int b0  = (bx & 31) * 32;
#pragma unroll
    for (int r = 0; r < 4; ++r) {        // stage convT tile (coalesced)
        int rr = r * 8 + (tid >> 5);     // b-offset
        int cc = tid & 31;               // i-offset
        cvl[rr][cc] = g_convT[(size_t)(b0 + rr) * 1024 + i0 + cc];
    }
    __syncthreads();
#pragma unroll
    for (int r = 0; r < 4; ++r) {
        int ii = r * 8 + (tid >> 5);
        int bb = tid & 31;
        float2 w2 = g_w2y[(size_t)(i0 + ii) * 1024 + b0 + bb];
        float2 cv = cvl[bb][ii];
        float re = w2.x + cv.x;
        float im = w2.y + cv.y;
        float mag = sqrtf(re * re + im * im);
        float s = fmaxf(mag - BETA_F, 0.0f) / fmaxf(mag, EPS_F);
        size_t o = (size_t)(i0 + ii) * 1024 + b0 + bb;
        if (o < (size_t)out_n) out[o] = re * s;
    }
}

// ---------------- launcher ---------------------------------------------------
extern "C" void kernel_launch(void* const* d_in, const int* in_sizes, int n_in,
                              void* d_out, int out_size, void* d_ws, size_t ws_size,
                              hipStream_t stream) {
    (void)d_ws; (void)ws_size; (void)in_sizes; (void)n_in;
    const float* v_re  = (const float*)d_in[0];
    const float* v_im  = (const float*)d_in[1];
    const float* W2_re = (const float*)d_in[2];
    const float* W2_im = (const float*)d_in[3];
    const float* x_re  = (const float*)d_in[4];
    const float* x_im  = (const float*)d_in[5];
    const float* y_re  = (const float*)d_in[6];
    const float* y_im  = (const float*)d_in[7];
    float* out = (float*)d_out;

    build_all<<<1537, 256, 0, stream>>>(v_re, v_im, W2_re, W2_im,
                                        x_re, x_im, y_re, y_im);
    gemm_w2y<<<512, 256, 0, stream>>>();
    fft_conv<<<512, 256, 0, stream>>>();
    combine<<<1024, 256, 0, stream>>>(out, out_size);
}

// Round 8
// 112.343 us; speedup vs baseline: 1.2571x; 1.2571x over previous
//
#include <hip/hip_runtime.h>
#include <hip/hip_fp16.h>
#include <cstdint>
#include <cstddef>

// z = soft_thresh(Toeplitz(v) @ x + W2 @ y, beta) -- complex, N=1024, M=256, B=1024
// Output = Re(z) only: [1024,1024] f32.
//
// R26: FFT path kept (R25 passed; fft_conv profiled at 45us with 1.26e7 LDS
// bank conflicts = the dominant cost). fft_conv rewritten:
//  - padded LDS phys(i)=i+(i>>4) (data conflicts 16-way -> <=4-way)
//  - per-stage twiddle tables (consecutive-j reads, conflict-free)
//  - stage-PAIRED radix-2 (2 layers per LDS round-trip): 24 -> 12 barriers,
//    LDS traffic halved; arithmetic op-for-op identical to R25
//  - first fwd stage folded into load (upper half zero); last inv stage
//    folded into store (only lower 1024 outputs)
//  - 128-thr blocks, 1 column each, 1024 blocks (4 blocks/CU, 33.8KB LDS)
// combine kernel + g_w2y eliminated: gemm_w2y (runs after fft_conv) fuses
// conv-add + soft-threshold in its epilogue (reads g_convT). 3 launches total.

#define BETA_F 0.01f
#define EPS_F  1e-12f

typedef __attribute__((ext_vector_type(8))) _Float16 half8;
typedef __attribute__((ext_vector_type(4))) _Float16 half4;
typedef __attribute__((ext_vector_type(4))) float   floatx4;

__device__ alignas(16) _Float16 g_A2[1024 * 512];        // 1 MB  [W2_re | W2_im]
__device__ alignas(16) _Float16 g_B2t[2048 * 512];       // 2 MB  [y embedding]^T
__device__ alignas(16) float2   g_xT[1024 * 1024];       // 8 MB  xT[b][n]
__device__ alignas(16) float2   g_V[2048];               // FFT(u~)/2048, bitrev order
__device__ alignas(16) float2   g_convT[1024 * 1024];    // 8 MB  conv^T[b][i]

// ---------------- prep: A2', B2t, xT, V --------------------------------------
__global__ __launch_bounds__(256) void build_all(
    const float* __restrict__ v_re, const float* __restrict__ v_im,
    const float* __restrict__ W2_re, const float* __restrict__ W2_im,
    const float* __restrict__ x_re, const float* __restrict__ x_im,
    const float* __restrict__ y_re, const float* __restrict__ y_im)
{
    __shared__ __align__(16) char sbuf[24576];
    const int bx  = blockIdx.x;
    const int tid = threadIdx.x;

    if (bx < 256) {                            // ---- A2'[1024][512] fp16
        int t  = bx * 256 + tid;
        int i  = t >> 6;
        int kp = (t & 63) * 8;
        half8 h;
        if (kp < 256) {
            const float* s = W2_re + i * 256 + kp;
#pragma unroll
            for (int j = 0; j < 8; ++j) h[j] = (_Float16)s[j];
        } else {
            const float* s = W2_im + i * 256 + (kp - 256);
#pragma unroll
            for (int j = 0; j < 8; ++j) h[j] = (_Float16)s[j];
        }
        *reinterpret_cast<half8*>(g_A2 + (size_t)i * 512 + kp) = h;
        return;
    }
    if (bx < 512) {                            // ---- B2t[2048][512] fp16 (y^T)
        float (*lre)[33] = (float(*)[33])sbuf;
        float (*lim)[33] = (float(*)[33])(sbuf + 4224);
        int idx = bx - 256;
        int bk  = idx & 7;
        int by  = idx >> 3;
        int k0  = bk * 32;
        int n0  = by * 32;
        {
            int kk  = tid >> 3;
            int tx4 = (tid & 7) * 4;
            const floatx4 re4 = *reinterpret_cast<const floatx4*>(
                y_re + (size_t)(k0 + kk) * 1024 + n0 + tx4);
            const floatx4 im4 = *reinterpret_cast<const floatx4*>(
                y_im + (size_t)(k0 + kk) * 1024 + n0 + tx4);
#pragma unroll
            for (int j = 0; j < 4; ++j) {
                lre[kk][tx4 + j] = re4[j];
                lim[kk][tx4 + j] = im4[j];
            }
        }
        __syncthreads();
        int lane_n = tid >> 3;
        int kq     = (tid & 7) * 4;
        half4 hre, him, hmim;
#pragma unroll
        for (int j = 0; j < 4; ++j) {
            float re = lre[kq + j][lane_n];
            float im = lim[kq + j][lane_n];
            hre[j]  = (_Float16)re;
            him[j]  = (_Float16)im;
            hmim[j] = (_Float16)(-im);
        }
        int n = n0 + lane_n;
        _Float16* r0 = g_B2t + (size_t)(2 * n)     * 512;
        _Float16* r1 = g_B2t + (size_t)(2 * n + 1) * 512;
        *reinterpret_cast<half4*>(r0 + k0 + kq)       = hre;
        *reinterpret_cast<half4*>(r0 + 256 + k0 + kq) = hmim;
        *reinterpret_cast<half4*>(r1 + k0 + kq)       = him;
        *reinterpret_cast<half4*>(r1 + 256 + k0 + kq) = hre;
        return;
    }
    if (bx < 1536) {                           // ---- xT[b][n] float2 (x^T)
        float (*lre)[33] = (float(*)[33])sbuf;
        float (*lim)[33] = (float(*)[33])(sbuf + 4224);
        int idx = bx - 512;
        int n0  = (idx >> 5) * 32;
        int b0  = (idx & 31) * 32;
        {
            int kk  = tid >> 3;
            int tx4 = (tid & 7) * 4;
            const floatx4 re4 = *reinterpret_cast<const floatx4*>(
                x_re + (size_t)(n0 + kk) * 1024 + b0 + tx4);
            const floatx4 im4 = *reinterpret_cast<const floatx4*>(
                x_im + (size_t)(n0 + kk) * 1024 + b0 + tx4);
#pragma unroll
            for (int j = 0; j < 4; ++j) {
                lre[kk][tx4 + j] = re4[j];
                lim[kk][tx4 + j] = im4[j];
            }
        }
        __syncthreads();
        int bb  = tid >> 3;
        int nn4 = (tid & 7) * 4;
        float2* dst = g_xT + (size_t)(b0 + bb) * 1024 + n0 + nn4;
        floatx4 w0, w1;
        w0[0] = lre[nn4 + 0][bb]; w0[1] = lim[nn4 + 0][bb];
        w0[2] = lre[nn4 + 1][bb]; w0[3] = lim[nn4 + 1][bb];
        w1[0] = lre[nn4 + 2][bb]; w1[1] = lim[nn4 + 2][bb];
        w1[2] = lre[nn4 + 3][bb]; w1[3] = lim[nn4 + 3][bb];
        *reinterpret_cast<floatx4*>(dst)     = w0;
        *reinterpret_cast<floatx4*>(dst + 2) = w1;
        return;
    }
    // ---- bx == 1536: V = DIF-FFT_2048(u~) * (1/2048), bit-reversed order ----
    float2* du = (float2*)sbuf;
    float*  twr = (float*)(sbuf + 16384);
    float*  twi = (float*)(sbuf + 20480);
#pragma unroll
    for (int r = 0; r < 4; ++r) {
        int k = tid + 256 * r;
        float ang = (float)k * 3.0679615757712823e-3f;
        float s, c;
        __sincosf(ang, &s, &c);
        twr[k] = c; twi[k] = -s;
    }
#pragma unroll
    for (int r = 0; r < 8; ++r) {
        int k = tid + 256 * r;
        float2 val;
        if (k < 1024)      { val.x = v_re[1023 + k]; val.y = v_im[1023 + k]; }
        else if (k == 1024){ val.x = 0.f; val.y = 0.f; }
        else               { val.x = v_re[k - 1025]; val.y = v_im[k - 1025]; }
        du[k] = val;
    }
    for (int s = 0; s < 11; ++s) {
        int lh = 10 - s, h = 1 << lh;
        __syncthreads();
#pragma unroll
        for (int r = 0; r < 4; ++r) {
            int i  = tid + 256 * r;
            int j  = i & (h - 1);
            int i0 = ((i >> lh) << (lh + 1)) | j;
            int i1 = i0 + h;
            float2 a = du[i0], b = du[i1];
            float dx = a.x - b.x, dy = a.y - b.y;
            int ti = j << s;
            float wr = twr[ti], wi = twi[ti];
            float2 s0; s0.x = a.x + b.x; s0.y = a.y + b.y;
            float2 d0; d0.x = dx * wr - dy * wi; d0.y = dx * wi + dy * wr;
            du[i0] = s0; du[i1] = d0;
        }
    }
    __syncthreads();
#pragma unroll
    for (int r = 0; r < 8; ++r) {
        int k = tid + 256 * r;
        float2 v = du[k];
        v.x *= (1.0f / 2048.0f); v.y *= (1.0f / 2048.0f);
        g_V[k] = v;
    }
}

// ---------------- FFT convolution v2 -----------------------------------------
// 1024 blocks x 128 thr, 1 column each. Padded LDS (i + (i>>4)); per-stage
// twiddle tables (2047 float2, consecutive-j); stage-paired radix-2 (12
// barriers); fwd stage0 folded into load, inv stage10 folded into store.
#define PHYS(i) ((i) + ((i) >> 4))
__global__ __launch_bounds__(128, 2) void fft_conv()
{
    __shared__ float2 dat[2176];       // 2048 padded
    __shared__ float2 twl[2047];       // T_s[j]=W^(j*2^s); off(0)=0, off(s)=2048-2^(11-s)

    const int tl = threadIdx.x;        // 0..127
    const int b  = blockIdx.x;         // column

    {   // build per-stage twiddle tables
        int off = 0;
        for (int s = 0; s <= 10; ++s) {
            int len = 1 << (10 - s);
            for (int j = tl; j < len; j += 128) {
                float ang = (float)(j << s) * 3.0679615757712823e-3f;  // 2pi/2048
                float sn, cs;
                __sincosf(ang, &sn, &cs);
                float2 t; t.x = cs; t.y = -sn;
                twl[off + j] = t;
            }
            off += len;
        }
    }
    __syncthreads();

    // load + folded forward stage s=0 (upper input half is zero)
    const float2* src = g_xT + (size_t)b * 1024;
#pragma unroll
    for (int r = 0; r < 8; ++r) {
        int i = tl + 128 * r;
        float2 v = src[i];
        float2 w = twl[i];                       // T_0[i]
        dat[PHYS(i)] = v;
        int iu = i + 1024;
        float2 m; m.x = v.x * w.x - v.y * w.y; m.y = v.x * w.y + v.y * w.x;
        dat[PHYS(iu)] = m;
    }
    __syncthreads();

    // forward DIF stage pairs (s, s+1), s = 1,3,5,7,9
#pragma unroll
    for (int sp = 0; sp < 5; ++sp) {
        const int s     = 1 + 2 * sp;
        const int lh    = 10 - s;
        const int q     = 1 << (lh - 1);
        const int offS  = 2048 - (1 << (11 - s));
        const int offS1 = 2048 - (1 << (10 - s));
#pragma unroll
        for (int gg = 0; gg < 4; ++gg) {
            int g    = tl + 128 * gg;
            int j    = g & (q - 1);
            int base = (g >> (lh - 1)) << (lh + 1);
            int b0 = base + j, b1 = b0 + q, b2 = b0 + 2 * q, b3 = b0 + 3 * q;
            float2 d0 = dat[PHYS(b0)], d1 = dat[PHYS(b1)];
            float2 d2 = dat[PHYS(b2)], d3 = dat[PHYS(b3)];
            float2 tS0 = twl[offS + j];
            float2 tS1 = twl[offS + j + q];
            float2 tT  = twl[offS1 + j];
            float2 u0, u1, v0, v1, tm;
            u0.x = d0.x + d2.x; u0.y = d0.y + d2.y;
            tm.x = d0.x - d2.x; tm.y = d0.y - d2.y;
            v0.x = tm.x * tS0.x - tm.y * tS0.y; v0.y = tm.x * tS0.y + tm.y * tS0.x;
            u1.x = d1.x + d3.x; u1.y = d1.y + d3.y;
            tm.x = d1.x - d3.x; tm.y = d1.y - d3.y;
            v1.x = tm.x * tS1.x - tm.y * tS1.y; v1.y = tm.x * tS1.y + tm.y * tS1.x;
            float2 c0, c1, c2, c3;
            c0.x = u0.x + u1.x; c0.y = u0.y + u1.y;
            tm.x = u0.x - u1.x; tm.y = u0.y - u1.y;
            c1.x = tm.x * tT.x - tm.y * tT.y; c1.y = tm.x * tT.y + tm.y * tT.x;
            c2.x = v0.x + v1.x; c2.y = v0.y + v1.y;
            tm.x = v0.x - v1.x; tm.y = v0.y - v1.y;
            c3.x = tm.x * tT.x - tm.y * tT.y; c3.y = tm.x * tT.y + tm.y * tT.x;
            dat[PHYS(b0)] = c0; dat[PHYS(b1)] = c1;
            dat[PHYS(b2)] = c2; dat[PHYS(b3)] = c3;
        }
        __syncthreads();
    }

    // pointwise multiply by V (bit-reversed domain; V pre-scaled by 1/2048)
#pragma unroll
    for (int r = 0; r < 16; ++r) {
        int k = tl + 128 * r;
        float2 a = dat[PHYS(k)];
        float2 v = g_V[k];
        float2 m; m.x = a.x * v.x - a.y * v.y; m.y = a.x * v.y + a.y * v.x;
        dat[PHYS(k)] = m;
    }
    __syncthreads();

    // inverse DIT stage pairs (ss, ss+1), ss = 0,2,4,6,8  (conj twiddles)
#pragma unroll
    for (int sp = 0; sp < 5; ++sp) {
        const int ss   = 2 * sp;
        const int h    = 1 << ss;
        const int offA = 2048 - (1 << (ss + 1));   // T_{10-ss}
        const int offB = 2048 - (1 << (ss + 2));   // T_{9-ss}
#pragma unroll
        for (int gg = 0; gg < 4; ++gg) {
            int g    = tl + 128 * gg;
            int j    = g & (h - 1);
            int base = (g >> ss) << (ss + 2);
            int b0 = base + j, b1 = b0 + h, b2 = b0 + 2 * h, b3 = b0 + 3 * h;
            float2 d0 = dat[PHYS(b0)], d1 = dat[PHYS(b1)];
            float2 d2 = dat[PHYS(b2)], d3 = dat[PHYS(b3)];
            float2 wA  = twl[offA + j];
            float2 wB0 = twl[offB + j];
            float2 wB1 = twl[offB + j + h];
            float2 t1; t1.x = d1.x * wA.x + d1.y * wA.y;  t1.y = d1.y * wA.x - d1.x * wA.y;
            float2 t3; t3.x = d3.x * wA.x + d3.y * wA.y;  t3.y = d3.y * wA.x - d3.x * wA.y;
            float2 e0, e1, e2, e3;
            e0.x = d0.x + t1.x; e0.y = d0.y + t1.y;
            e1.x = d0.x - t1.x; e1.y = d0.y - t1.y;
            e2.x = d2.x + t3.x; e2.y = d2.y + t3.y;
            e3.x = d2.x - t3.x; e3.y = d2.y - t3.y;
            float2 f2; f2.x = e2.x * wB0.x + e2.y * wB0.y; f2.y = e2.y * wB0.x - e2.x * wB0.y;
            float2 f3; f3.x = e3.x * wB1.x + e3.y * wB1.y; f3.y = e3.y * wB1.x - e3.x * wB1.y;
            float2 c0, c1, c2, c3;
            c0.x = e0.x + f2.x; c0.y = e0.y + f2.y;
            c2.x = e0.x - f2.x; c2.y = e0.y - f2.y;
            c1.x = e1.x + f3.x; c1.y = e1.y + f3.y;
            c3.x = e1.x - f3.x; c3.y = e1.y - f3.y;
            dat[PHYS(b0)] = c0; dat[PHYS(b1)] = c1;
            dat[PHYS(b2)] = c2; dat[PHYS(b3)] = c3;
        }
        __syncthreads();
    }

    // folded inverse stage ss=10 + store (only lower 1024 outputs needed)
    float2* dst = g_convT + (size_t)b * 1024;
#pragma unroll
    for (int r = 0; r < 8; ++r) {
        int i  = tl + 128 * r;
        int iu = i + 1024;
        float2 a  = dat[PHYS(i)];
        float2 bb = dat[PHYS(iu)];
        float2 w  = twl[i];                       // T_0[i], conj applied inline
        float2 t; t.x = bb.x * w.x + bb.y * w.y; t.y = bb.y * w.x - bb.x * w.y;
        float2 o; o.x = a.x + t.x; o.y = a.y + t.y;
        dst[i] = o;
    }
}

// ---------------- W2@y GEMM (K=512) + fused conv-add + soft-threshold --------
// R13 structure: 512 blocks (2/CU), 256 thr (4 waves 2x2), 64x64 tile, BK=128,
// NIT=4, dbuf LDS 64KB, 2-deep reg prefetch, XOR swizzle, 1 barrier/iter.
// Runs AFTER fft_conv: epilogue reads g_convT, adds, thresholds, writes out.
__global__ __launch_bounds__(256, 2) void gemm_w2y(float* __restrict__ out,
                                                   int out_n)
{
    __shared__ __align__(16) _Float16 As[2 * 4 * 64 * 32];
    __shared__ __align__(16) _Float16 Bs[2 * 4 * 64 * 32];

    const int tid  = threadIdx.x;
    const int lane = tid & 63;
    const int w    = tid >> 6;
    const int wm   = w >> 1;
    const int wn   = w & 1;

    const int bid = blockIdx.x;
    const int xcd = bid & 7;
    const int t   = bid >> 3;
    const int mi0 = ((xcd & 1) * 8 + (t & 7)) * 64;
    const int ni0 = ((xcd >> 1) * 8 + (t >> 3)) * 64;

    floatx4 acc[2][2];
#pragma unroll
    for (int a = 0; a < 2; ++a)
#pragma unroll
        for (int b = 0; b < 2; ++b) acc[a][b] = (floatx4)0.0f;

    const int rS = tid >> 2;
    const int jS = tid & 3;
    const int s0 = ((rS & 15) >> 1) & 3;
    char* asW = (char*)As + rS * 64 + ((jS ^ s0) * 16);
    char* bsW = (char*)Bs + rS * 64 + ((jS ^ s0) * 16);
    const _Float16* gA = g_A2  + (size_t)(mi0 + rS) * 512 + jS * 8;
    const _Float16* gB = g_B2t + (size_t)(ni0 + rS) * 512 + jS * 8;

    const int rowA = lane & 15;
    const int q    = lane >> 4;
    const int coff = (q ^ ((rowA >> 1) & 3)) * 16;

    const int NIT = 512 / 128;           // 4

    half8 sA[2][4], sB[2][4];
    {
        half8 tA[4], tB[4];
#pragma unroll
        for (int ks = 0; ks < 4; ++ks) {
            tA[ks] = *reinterpret_cast<const half8*>(gA + ks * 32);
            tB[ks] = *reinterpret_cast<const half8*>(gB + ks * 32);
        }
#pragma unroll
        for (int ks = 0; ks < 4; ++ks) {
            sA[1][ks] = *reinterpret_cast<const half8*>(gA + 128 + ks * 32);
            sB[1][ks] = *reinterpret_cast<const half8*>(gB + 128 + ks * 32);
        }
#pragma unroll
        for (int ks = 0; ks < 4; ++ks) {
            *reinterpret_cast<half8*>(asW + ks * 4096) = tA[ks];
            *reinterpret_cast<half8*>(bsW + ks * 4096) = tB[ks];
        }
    }
    __syncthreads();

#pragma unroll 2
    for (int kt = 0; kt < NIT; ++kt) {
        const int cur = kt & 1;
        const int nxt = cur ^ 1;
        if (kt + 2 < NIT) {
            const _Float16* ga = gA + (size_t)(kt + 2) * 128;
            const _Float16* gb = gB + (size_t)(kt + 2) * 128;
#pragma unroll
            for (int ks = 0; ks < 4; ++ks) {
                sA[cur][ks] = *reinterpret_cast<const half8*>(ga + ks * 32);
                sB[cur][ks] = *reinterpret_cast<const half8*>(gb + ks * 32);
            }
        }
        const char* Ab = (const char*)As + cur * 16384;
        const char* Bb = (const char*)Bs + cur * 16384;
#pragma unroll
        for (int ks = 0; ks < 4; ++ks) {
            half8 af[2], bf[2];
#pragma unroll
            for (int mi = 0; mi < 2; ++mi) {
                int r = wm * 32 + mi * 16 + rowA;
                af[mi] = *reinterpret_cast<const half8*>(Ab + ks * 4096 + r * 64 + coff);
            }
#pragma unroll
            for (int ni = 0; ni < 2; ++ni) {
                int r = wn * 32 + ni * 16 + rowA;
                bf[ni] = *reinterpret_cast<const half8*>(Bb + ks * 4096 + r * 64 + coff);
            }
#pragma unroll
            for (int mi = 0; mi < 2; ++mi)
#pragma unroll
                for (int ni = 0; ni < 2; ++ni)
                    acc[mi][ni] = __builtin_amdgcn_mfma_f32_16x16x32_f16(
                        af[mi], bf[ni], acc[mi][ni], 0, 0, 0);
        }
        if (kt + 1 < NIT) {
            char* aw = asW + nxt * 16384;
            char* bw = bsW + nxt * 16384;
#pragma unroll
            for (int ks = 0; ks < 4; ++ks) {
                *reinterpret_cast<half8*>(aw + ks * 4096) = sA[nxt][ks];
                *reinterpret_cast<half8*>(bw + ks * 4096) = sB[nxt][ks];
            }
        }
        __syncthreads();
    }

    // epilogue: lane pair (even,odd) = (Re,Im); add conv, threshold, store Re.
    const int colL  = lane & 15;
    const int rquad = (lane >> 4) * 4;
#pragma unroll
    for (int mi = 0; mi < 2; ++mi)
#pragma unroll
        for (int ni = 0; ni < 2; ++ni)
#pragma unroll
            for (int r = 0; r < 4; ++r) {
                float c = acc[mi][ni][r];
                float p = __shfl_xor(c, 1, 64);
                if (!(colL & 1)) {
                    int row  = mi0 + wm * 32 + mi * 16 + rquad + r;
                    int col  = ni0 + wn * 32 + ni * 16 + colL;
                    int bcol = col >> 1;
                    float2 cv = g_convT[(size_t)bcol * 1024 + row];
                    float re = c + cv.x;
                    float im = p + cv.y;
                    float mag = sqrtf(re * re + im * im);
                    float s = fmaxf(mag - BETA_F, 0.0f) / fmaxf(mag, EPS_F);
                    size_t o = (size_t)row * 1024 + bcol;
                    if (o < (size_t)out_n) out[o] = re * s;
                }
            }
}

// ---------------- launcher ---------------------------------------------------
extern "C" void kernel_launch(void* const* d_in, const int* in_sizes, int n_in,
                              void* d_out, int out_size, void* d_ws, size_t ws_size,
                              hipStream_t stream) {
    (void)d_ws; (void)ws_size; (void)in_sizes; (void)n_in;
    const float* v_re  = (const float*)d_in[0];
    const float* v_im  = (const float*)d_in[1];
    const float* W2_re = (const float*)d_in[2];
    const float* W2_im = (const float*)d_in[3];
    const float* x_re  = (const float*)d_in[4];
    const float* x_im  = (const float*)d_in[5];
    const float* y_re  = (const float*)d_in[6];
    const float* y_im  = (const float*)d_in[7];
    float* out = (float*)d_out;

    build_all<<<1537, 256, 0, stream>>>(v_re, v_im, W2_re, W2_im,
                                        x_re, x_im, y_re, y_im);
    fft_conv<<<1024, 128, 0, stream>>>();
    gemm_w2y<<<512, 256, 0, stream>>>(out, out_size);
}

// Round 9
// 105.408 us; speedup vs baseline: 1.3398x; 1.0658x over previous
//
#include <hip/hip_runtime.h>
#include <hip/hip_fp16.h>
#include <cstdint>
#include <cstddef>

// z = soft_thresh(Toeplitz(v) @ x + W2 @ y, beta) -- complex, N=1024, M=256, B=1024
// Output = Re(z) only: [1024,1024] f32.
//
// R27: register-resident FFT. Thread t holds x[t+128r] (16 f2 regs):
// DIF s=0..3 are register-local; LDS exchange -> x[128q+u+8k]: s=4..7 local;
// exchange -> x[16t+k]: s=8..10 + pointwise(V) + inverse ss=0..2 local;
// mirror exchanges back for ss=3..6 and ss=7..10. 4 LDS round trips / 4
// barriers (dbuf) vs R26's 12/12. phys(L)=L+(L>>4): all exchange patterns at
// the 4-lane/bank b64 floor. Twiddles via __sincosf (no tables). Butterflies
// op-identical to the verified R25/R26 sequences.
// gemm_w2y epilogue: scattered convT gathers -> coalesced LDS-staged tile.

#define BETA_F 0.01f
#define EPS_F  1e-12f
#define TWN 3.0679615757712823e-3f    // 2*pi/2048

typedef __attribute__((ext_vector_type(8))) _Float16 half8;
typedef __attribute__((ext_vector_type(4))) _Float16 half4;
typedef __attribute__((ext_vector_type(4))) float   floatx4;

__device__ alignas(16) _Float16 g_A2[1024 * 512];        // 1 MB  [W2_re | W2_im]
__device__ alignas(16) _Float16 g_B2t[2048 * 512];       // 2 MB  [y embedding]^T
__device__ alignas(16) float2   g_xT[1024 * 1024];       // 8 MB  xT[b][n]
__device__ alignas(16) float2   g_V[2048];               // FFT(u~)/2048, bitrev order
__device__ alignas(16) float2   g_convT[1024 * 1024];    // 8 MB  conv^T[b][i]

// ---------------- prep: A2', B2t, xT, V (unchanged from R26, passed) ---------
__global__ __launch_bounds__(256) void build_all(
    const float* __restrict__ v_re, const float* __restrict__ v_im,
    const float* __restrict__ W2_re, const float* __restrict__ W2_im,
    const float* __restrict__ x_re, const float* __restrict__ x_im,
    const float* __restrict__ y_re, const float* __restrict__ y_im)
{
    __shared__ __align__(16) char sbuf[24576];
    const int bx  = blockIdx.x;
    const int tid = threadIdx.x;

    if (bx < 256) {                            // ---- A2'[1024][512] fp16
        int t  = bx * 256 + tid;
        int i  = t >> 6;
        int kp = (t & 63) * 8;
        half8 h;
        if (kp < 256) {
            const float* s = W2_re + i * 256 + kp;
#pragma unroll
            for (int j = 0; j < 8; ++j) h[j] = (_Float16)s[j];
        } else {
            const float* s = W2_im + i * 256 + (kp - 256);
#pragma unroll
            for (int j = 0; j < 8; ++j) h[j] = (_Float16)s[j];
        }
        *reinterpret_cast<half8*>(g_A2 + (size_t)i * 512 + kp) = h;
        return;
    }
    if (bx < 512) {                            // ---- B2t[2048][512] fp16 (y^T)
        float (*lre)[33] = (float(*)[33])sbuf;
        float (*lim)[33] = (float(*)[33])(sbuf + 4224);
        int idx = bx - 256;
        int bk  = idx & 7;
        int by  = idx >> 3;
        int k0  = bk * 32;
        int n0  = by * 32;
        {
            int kk  = tid >> 3;
            int tx4 = (tid & 7) * 4;
            const floatx4 re4 = *reinterpret_cast<const floatx4*>(
                y_re + (size_t)(k0 + kk) * 1024 + n0 + tx4);
            const floatx4 im4 = *reinterpret_cast<const floatx4*>(
                y_im + (size_t)(k0 + kk) * 1024 + n0 + tx4);
#pragma unroll
            for (int j = 0; j < 4; ++j) {
                lre[kk][tx4 + j] = re4[j];
                lim[kk][tx4 + j] = im4[j];
            }
        }
        __syncthreads();
        int lane_n = tid >> 3;
        int kq     = (tid & 7) * 4;
        half4 hre, him, hmim;
#pragma unroll
        for (int j = 0; j < 4; ++j) {
            float re = lre[kq + j][lane_n];
            float im = lim[kq + j][lane_n];
            hre[j]  = (_Float16)re;
            him[j]  = (_Float16)im;
            hmim[j] = (_Float16)(-im);
        }
        int n = n0 + lane_n;
        _Float16* r0 = g_B2t + (size_t)(2 * n)     * 512;
        _Float16* r1 = g_B2t + (size_t)(2 * n + 1) * 512;
        *reinterpret_cast<half4*>(r0 + k0 + kq)       = hre;
        *reinterpret_cast<half4*>(r0 + 256 + k0 + kq) = hmim;
        *reinterpret_cast<half4*>(r1 + k0 + kq)       = him;
        *reinterpret_cast<half4*>(r1 + 256 + k0 + kq) = hre;
        return;
    }
    if (bx < 1536) {                           // ---- xT[b][n] float2 (x^T)
        float (*lre)[33] = (float(*)[33])sbuf;
        float (*lim)[33] = (float(*)[33])(sbuf + 4224);
        int idx = bx - 512;
        int n0  = (idx >> 5) * 32;
        int b0  = (idx & 31) * 32;
        {
            int kk  = tid >> 3;
            int tx4 = (tid & 7) * 4;
            const floatx4 re4 = *reinterpret_cast<const floatx4*>(
                x_re + (size_t)(n0 + kk) * 1024 + b0 + tx4);
            const floatx4 im4 = *reinterpret_cast<const floatx4*>(
                x_im + (size_t)(n0 + kk) * 1024 + b0 + tx4);
#pragma unroll
            for (int j = 0; j < 4; ++j) {
                lre[kk][tx4 + j] = re4[j];
                lim[kk][tx4 + j] = im4[j];
            }
        }
        __syncthreads();
        int bb  = tid >> 3;
        int nn4 = (tid & 7) * 4;
        float2* dst = g_xT + (size_t)(b0 + bb) * 1024 + n0 + nn4;
        floatx4 w0, w1;
        w0[0] = lre[nn4 + 0][bb]; w0[1] = lim[nn4 + 0][bb];
        w0[2] = lre[nn4 + 1][bb]; w0[3] = lim[nn4 + 1][bb];
        w1[0] = lre[nn4 + 2][bb]; w1[1] = lim[nn4 + 2][bb];
        w1[2] = lre[nn4 + 3][bb]; w1[3] = lim[nn4 + 3][bb];
        *reinterpret_cast<floatx4*>(dst)     = w0;
        *reinterpret_cast<floatx4*>(dst + 2) = w1;
        return;
    }
    // ---- bx == 1536: V = DIF-FFT_2048(u~) * (1/2048), bit-reversed order ----
    float2* du = (float2*)sbuf;
    float*  twr = (float*)(sbuf + 16384);
    float*  twi = (float*)(sbuf + 20480);
#pragma unroll
    for (int r = 0; r < 4; ++r) {
        int k = tid + 256 * r;
        float ang = (float)k * TWN;
        float s, c;
        __sincosf(ang, &s, &c);
        twr[k] = c; twi[k] = -s;
    }
#pragma unroll
    for (int r = 0; r < 8; ++r) {
        int k = tid + 256 * r;
        float2 val;
        if (k < 1024)      { val.x = v_re[1023 + k]; val.y = v_im[1023 + k]; }
        else if (k == 1024){ val.x = 0.f; val.y = 0.f; }
        else               { val.x = v_re[k - 1025]; val.y = v_im[k - 1025]; }
        du[k] = val;
    }
    for (int s = 0; s < 11; ++s) {
        int lh = 10 - s, h = 1 << lh;
        __syncthreads();
#pragma unroll
        for (int r = 0; r < 4; ++r) {
            int i  = tid + 256 * r;
            int j  = i & (h - 1);
            int i0 = ((i >> lh) << (lh + 1)) | j;
            int i1 = i0 + h;
            float2 a = du[i0], b = du[i1];
            float dx = a.x - b.x, dy = a.y - b.y;
            int ti = j << s;
            float wr = twr[ti], wi = twi[ti];
            float2 s0; s0.x = a.x + b.x; s0.y = a.y + b.y;
            float2 d0; d0.x = dx * wr - dy * wi; d0.y = dx * wi + dy * wr;
            du[i0] = s0; du[i1] = d0;
        }
    }
    __syncthreads();
#pragma unroll
    for (int r = 0; r < 8; ++r) {
        int k = tid + 256 * r;
        float2 v = du[k];
        v.x *= (1.0f / 2048.0f); v.y *= (1.0f / 2048.0f);
        g_V[k] = v;
    }
}

// ---------------- FFT convolution v3: register-resident ----------------------
// 1024 blocks x 128 thr, 1 column each. 16 f2/thread; 4 LDS exchanges (dbuf).
#define PHYS(L) ((L) + ((L) >> 4))
__global__ __launch_bounds__(128) void fft_conv()
{
    __shared__ float2 ex[2][2176];     // PHYS(2047)=2174; dbuf 34.8KB

    const int t = threadIdx.x;         // 0..127
    const int b = blockIdx.x;
    const int q = t >> 3, u = t & 7;

    float2 e[16];

    auto tw = [](int expo) {
        float sn, cs;
        __sincosf((float)expo * TWN, &sn, &cs);
        float2 w; w.x = cs; w.y = -sn;      // W^expo = exp(-i*2pi*expo/2048)
        return w;
    };
    auto fwd = [](float2& A, float2& B, float2 w) {
        float2 a = A, c = B;
        float dx = a.x - c.x, dy = a.y - c.y;
        A.x = a.x + c.x; A.y = a.y + c.y;
        B.x = dx * w.x - dy * w.y;          // d * w
        B.y = dx * w.y + dy * w.x;
    };
    auto inv = [](float2& A, float2& B, float2 w) {
        float2 a = A, c = B;                // t1 = c * conj(w)
        float tx = c.x * w.x + c.y * w.y;
        float ty = c.y * w.x - c.x * w.y;
        A.x = a.x + tx; A.y = a.y + ty;
        B.x = a.x - tx; B.y = a.y - ty;
    };

    // ---- load L0: e[r] = x~[t + 128 r]; upper half zero ----
    const float2* src = g_xT + (size_t)b * 1024;
#pragma unroll
    for (int r = 0; r < 8; ++r) e[r] = src[t + 128 * r];
#pragma unroll
    for (int r = 8; r < 16; ++r) { e[r].x = 0.f; e[r].y = 0.f; }

    // ---- forward s=0..3 (register-local in L0) ----
#pragma unroll
    for (int r = 0; r < 8; ++r) fwd(e[r], e[r + 8], tw(t + 128 * r));          // s=0
#pragma unroll
    for (int r0 = 0; r0 < 4; ++r0) {                                           // s=1
        float2 w = tw((t + 128 * r0) << 1);
        fwd(e[r0], e[r0 + 4], w); fwd(e[r0 + 8], e[r0 + 12], w);
    }
#pragma unroll
    for (int r0 = 0; r0 < 2; ++r0) {                                           // s=2
        float2 w = tw((t + 128 * r0) << 2);
#pragma unroll
        for (int g4 = 0; g4 < 4; ++g4) fwd(e[g4 * 4 + r0], e[g4 * 4 + r0 + 2], w);
    }
    {                                                                          // s=3
        float2 w = tw(t << 3);
#pragma unroll
        for (int g2 = 0; g2 < 8; ++g2) fwd(e[g2 * 2], e[g2 * 2 + 1], w);
    }

    // ---- exchange 1: L0 -> L1 (f[k] = x[128 q + u + 8 k]) ----
#pragma unroll
    for (int r = 0; r < 16; ++r) { int L = 128 * r + t; ex[0][PHYS(L)] = e[r]; }
    __syncthreads();
#pragma unroll
    for (int k = 0; k < 16; ++k) { int L = 128 * q + u + 8 * k; e[k] = ex[0][PHYS(L)]; }

    // ---- forward s=4..7 (register-local in L1) ----
#pragma unroll
    for (int k = 0; k < 8; ++k) fwd(e[k], e[k + 8], tw((u + 8 * k) << 4));     // s=4
#pragma unroll
    for (int k0 = 0; k0 < 4; ++k0) {                                           // s=5
        float2 w = tw((u + 8 * k0) << 5);
        fwd(e[k0], e[k0 + 4], w); fwd(e[k0 + 8], e[k0 + 12], w);
    }
#pragma unroll
    for (int k0 = 0; k0 < 2; ++k0) {                                           // s=6
        float2 w = tw((u + 8 * k0) << 6);
#pragma unroll
        for (int g4 = 0; g4 < 4; ++g4) fwd(e[g4 * 4 + k0], e[g4 * 4 + k0 + 2], w);
    }
    {                                                                          // s=7
        float2 w = tw(u << 7);
#pragma unroll
        for (int g2 = 0; g2 < 8; ++g2) fwd(e[g2 * 2], e[g2 * 2 + 1], w);
    }

    // ---- exchange 2: L1 -> L2 (g[k] = x[16 t + k]) ----
#pragma unroll
    for (int k = 0; k < 16; ++k) { int L = 128 * q + u + 8 * k; ex[1][PHYS(L)] = e[k]; }
    __syncthreads();
#pragma unroll
    for (int k = 0; k < 16; ++k) { int L = 16 * t + k; e[k] = ex[1][PHYS(L)]; }

    // ---- forward s=8..10 (register-local in L2) ----
#pragma unroll
    for (int c = 0; c < 4; ++c) {                                              // s=8
        float2 w = tw(c << 8);
        fwd(e[c], e[c + 4], w); fwd(e[c + 8], e[c + 12], w);
    }
#pragma unroll
    for (int g4 = 0; g4 < 4; ++g4) {                                           // s=9
        // c=0: w=1 ; c=1: w=(0,-1) -> d*w = (dy, -dx)
        fwd(e[g4 * 4], e[g4 * 4 + 2], (float2){1.f, 0.f});
        float2& A = e[g4 * 4 + 1]; float2& B = e[g4 * 4 + 3];
        float2 a = A, c2 = B;
        float dx = a.x - c2.x, dy = a.y - c2.y;
        A.x = a.x + c2.x; A.y = a.y + c2.y;
        B.x = dy; B.y = -dx;
    }
#pragma unroll
    for (int g2 = 0; g2 < 8; ++g2) {                                           // s=10
        float2 a = e[g2 * 2], c2 = e[g2 * 2 + 1];
        e[g2 * 2].x     = a.x + c2.x; e[g2 * 2].y     = a.y + c2.y;
        e[g2 * 2 + 1].x = a.x - c2.x; e[g2 * 2 + 1].y = a.y - c2.y;
    }

    // ---- pointwise * V (bit-reversed domain; V pre-scaled 1/2048) ----
#pragma unroll
    for (int k = 0; k < 16; ++k) {
        float2 v = g_V[16 * t + k];
        float2 a = e[k];
        e[k].x = a.x * v.x - a.y * v.y;
        e[k].y = a.x * v.y + a.y * v.x;
    }

    // ---- inverse ss=0..2 (register-local in L2) ----
#pragma unroll
    for (int g2 = 0; g2 < 8; ++g2) {                                           // ss=0
        float2 a = e[g2 * 2], c2 = e[g2 * 2 + 1];
        e[g2 * 2].x     = a.x + c2.x; e[g2 * 2].y     = a.y + c2.y;
        e[g2 * 2 + 1].x = a.x - c2.x; e[g2 * 2 + 1].y = a.y - c2.y;
    }
#pragma unroll
    for (int g4 = 0; g4 < 4; ++g4) {                                           // ss=1
        inv(e[g4 * 4], e[g4 * 4 + 2], (float2){1.f, 0.f});
        // c=1: conj(w)= (0,1): t1 = c*(0,-1)conj -> t1 = (-c.y, c.x)
        float2& A = e[g4 * 4 + 1]; float2& B = e[g4 * 4 + 3];
        float2 a = A, c2 = B;
        float tx = -c2.y, ty = c2.x;
        A.x = a.x + tx; A.y = a.y + ty;
        B.x = a.x - tx; B.y = a.y - ty;
    }
#pragma unroll
    for (int c = 0; c < 4; ++c) {                                              // ss=2
        float2 w = tw(c << 8);
        inv(e[c], e[c + 4], w); inv(e[c + 8], e[c + 12], w);
    }

    // ---- exchange 3: L2 -> L1 ----
#pragma unroll
    for (int k = 0; k < 16; ++k) { int L = 16 * t + k; ex[0][PHYS(L)] = e[k]; }
    __syncthreads();
#pragma unroll
    for (int k = 0; k < 16; ++k) { int L = 128 * q + u + 8 * k; e[k] = ex[0][PHYS(L)]; }

    // ---- inverse ss=3..6 (register-local in L1) ----
    {                                                                          // ss=3
        float2 w = tw(u << 7);
#pragma unroll
        for (int g2 = 0; g2 < 8; ++g2) inv(e[g2 * 2], e[g2 * 2 + 1], w);
    }
#pragma unroll
    for (int k0 = 0; k0 < 2; ++k0) {                                           // ss=4
        float2 w = tw((u + 8 * k0) << 6);
#pragma unroll
        for (int g4 = 0; g4 < 4; ++g4) inv(e[g4 * 4 + k0], e[g4 * 4 + k0 + 2], w);
    }
#pragma unroll
    for (int k0 = 0; k0 < 4; ++k0) {                                           // ss=5
        float2 w = tw((u + 8 * k0) << 5);
        inv(e[k0], e[k0 + 4], w); inv(e[k0 + 8], e[k0 + 12], w);
    }
#pragma unroll
    for (int k = 0; k < 8; ++k) inv(e[k], e[k + 8], tw((u + 8 * k) << 4));     // ss=6

    // ---- exchange 4: L1 -> L0 ----
#pragma unroll
    for (int k = 0; k < 16; ++k) { int L = 128 * q + u + 8 * k; ex[1][PHYS(L)] = e[k]; }
    __syncthreads();
#pragma unroll
    for (int r = 0; r < 16; ++r) { int L = 128 * r + t; e[r] = ex[1][PHYS(L)]; }

    // ---- inverse ss=7..10 (register-local in L0) ----
    {                                                                          // ss=7
        float2 w = tw(t << 3);
#pragma unroll
        for (int g2 = 0; g2 < 8; ++g2) inv(e[g2 * 2], e[g2 * 2 + 1], w);
    }
#pragma unroll
    for (int r0 = 0; r0 < 2; ++r0) {                                           // ss=8
        float2 w = tw((t + 128 * r0) << 2);
#pragma unroll
        for (int g4 = 0; g4 < 4; ++g4) inv(e[g4 * 4 + r0], e[g4 * 4 + r0 + 2], w);
    }
#pragma unroll
    for (int r0 = 0; r0 < 4; ++r0) {                                           // ss=9
        float2 w = tw((t + 128 * r0) << 1);
        inv(e[r0], e[r0 + 4], w); inv(e[r0 + 8], e[r0 + 12], w);
    }
    // ss=10: only lower outputs needed: e[r] = a + b*conj(w)
    float2* dst = g_convT + (size_t)b * 1024;
#pragma unroll
    for (int r = 0; r < 8; ++r) {
        float2 w = tw(t + 128 * r);
        float2 a = e[r], c2 = e[r + 8];
        float tx = c2.x * w.x + c2.y * w.y;
        float ty = c2.y * w.x - c2.x * w.y;
        float2 o; o.x = a.x + tx; o.y = a.y + ty;
        dst[t + 128 * r] = o;
    }
}

// ---------------- W2@y GEMM (K=512) + fused conv-add + soft-threshold --------
// R13 structure; epilogue now LDS-stages the conv tile (coalesced) before use.
__global__ __launch_bounds__(256, 2) void gemm_w2y(float* __restrict__ out,
                                                   int out_n)
{
    __shared__ __align__(16) _Float16 As[2 * 4 * 64 * 32];
    __shared__ __align__(16) _Float16 Bs[2 * 4 * 64 * 32];

    const int tid  = threadIdx.x;
    const int lane = tid & 63;
    const int w    = tid >> 6;
    const int wm   = w >> 1;
    const int wn   = w & 1;

    const int bid = blockIdx.x;
    const int xcd = bid & 7;
    const int t   = bid >> 3;
    const int mi0 = ((xcd & 1) * 8 + (t & 7)) * 64;
    const int ni0 = ((xcd >> 1) * 8 + (t >> 3)) * 64;

    floatx4 acc[2][2];
#pragma unroll
    for (int a = 0; a < 2; ++a)
#pragma unroll
        for (int b = 0; b < 2; ++b) acc[a][b] = (floatx4)0.0f;

    const int rS = tid >> 2;
    const int jS = tid & 3;
    const int s0 = ((rS & 15) >> 1) & 3;
    char* asW = (char*)As + rS * 64 + ((jS ^ s0) * 16);
    char* bsW = (char*)Bs + rS * 64 + ((jS ^ s0) * 16);
    const _Float16* gA = g_A2  + (size_t)(mi0 + rS) * 512 + jS * 8;
    const _Float16* gB = g_B2t + (size_t)(ni0 + rS) * 512 + jS * 8;

    const int rowA = lane & 15;
    const int q    = lane >> 4;
    const int coff = (q ^ ((rowA >> 1) & 3)) * 16;

    const int NIT = 512 / 128;           // 4

    half8 sA[2][4], sB[2][4];
    {
        half8 tA[4], tB[4];
#pragma unroll
        for (int ks = 0; ks < 4; ++ks) {
            tA[ks] = *reinterpret_cast<const half8*>(gA + ks * 32);
            tB[ks] = *reinterpret_cast<const half8*>(gB + ks * 32);
        }
#pragma unroll
        for (int ks = 0; ks < 4; ++ks) {
            sA[1][ks] = *reinterpret_cast<const half8*>(gA + 128 + ks * 32);
            sB[1][ks] = *reinterpret_cast<const half8*>(gB + 128 + ks * 32);
        }
#pragma unroll
        for (int ks = 0; ks < 4; ++ks) {
            *reinterpret_cast<half8*>(asW + ks * 4096) = tA[ks];
            *reinterpret_cast<half8*>(bsW + ks * 4096) = tB[ks];
        }
    }
    __syncthreads();

#pragma unroll 2
    for (int kt = 0; kt < NIT; ++kt) {
        const int cur = kt & 1;
        const int nxt = cur ^ 1;
        if (kt + 2 < NIT) {
            const _Float16* ga = gA + (size_t)(kt + 2) * 128;
            const _Float16* gb = gB + (size_t)(kt + 2) * 128;
#pragma unroll
            for (int ks = 0; ks < 4; ++ks) {
                sA[cur][ks] = *reinterpret_cast<const half8*>(ga + ks * 32);
                sB[cur][ks] = *reinterpret_cast<const half8*>(gb + ks * 32);
            }
        }
        const char* Ab = (const char*)As + cur * 16384;
        const char* Bb = (const char*)Bs + cur * 16384;
#pragma unroll
        for (int ks = 0; ks < 4; ++ks) {
            half8 af[2], bf[2];
#pragma unroll
            for (int mi = 0; mi < 2; ++mi) {
                int r = wm * 32 + mi * 16 + rowA;
                af[mi] = *reinterpret_cast<const half8*>(Ab + ks * 4096 + r * 64 + coff);
            }
#pragma unroll
            for (int ni = 0; ni < 2; ++ni) {
                int r = wn * 32 + ni * 16 + rowA;
                bf[ni] = *reinterpret_cast<const half8*>(Bb + ks * 4096 + r * 64 + coff);
            }
#pragma unroll
            for (int mi = 0; mi < 2; ++mi)
#pragma unroll
                for (int ni = 0; ni < 2; ++ni)
                    acc[mi][ni] = __builtin_amdgcn_mfma_f32_16x16x32_f16(
                        af[mi], bf[ni], acc[mi][ni], 0, 0, 0);
        }
        if (kt + 1 < NIT) {
            char* aw = asW + nxt * 16384;
            char* bw = bsW + nxt * 16384;
#pragma unroll
            for (int ks = 0; ks < 4; ++ks) {
                *reinterpret_cast<half8*>(aw + ks * 4096) = sA[nxt][ks];
                *reinterpret_cast<half8*>(bw + ks * 4096) = sB[nxt][ks];
            }
        }
        __syncthreads();
    }

    // ---- stage conv tile (coalesced) into LDS: Lc[32][64], stride 66 --------
    float2* Lc = (float2*)As;            // K-loop done (barrier passed), As free
    {
        const int bl  = tid >> 3;        // 0..31
        const int il8 = (tid & 7) * 8;   // 0..56
        const float2* gsc = g_convT + (size_t)((ni0 >> 1) + bl) * 1024 + mi0 + il8;
#pragma unroll
        for (int j = 0; j < 8; j += 2) {
            floatx4 v = *reinterpret_cast<const floatx4*>(gsc + j);
            *reinterpret_cast<floatx4*>(Lc + bl * 66 + il8 + j) = v;
        }
    }
    __syncthreads();

    // epilogue: lane pair (even,odd) = (Re,Im); add conv, threshold, store Re.
    const int colL  = lane & 15;
    const int rquad = (lane >> 4) * 4;
#pragma unroll
    for (int mi = 0; mi < 2; ++mi)
#pragma unroll
        for (int ni = 0; ni < 2; ++ni)
#pragma unroll
            for (int r = 0; r < 4; ++r) {
                float c = acc[mi][ni][r];
                float p = __shfl_xor(c, 1, 64);
                if (!(colL & 1)) {
                    int bl2 = (wn * 32 + ni * 16 + colL) >> 1;   // 0..31
                    int il2 = wm * 32 + mi * 16 + rquad + r;     // 0..63
                    float2 cv = Lc[bl2 * 66 + il2];
                    float re = c + cv.x;
                    float im = p + cv.y;
                    float mag = sqrtf(re * re + im * im);
                    float s = fmaxf(mag - BETA_F, 0.0f) / fmaxf(mag, EPS_F);
                    int row  = mi0 + il2;
                    int bcol = (ni0 >> 1) + bl2;
                    size_t o = (size_t)row * 1024 + bcol;
                    if (o < (size_t)out_n) out[o] = re * s;
                }
            }
}

// ---------------- launcher ---------------------------------------------------
extern "C" void kernel_launch(void* const* d_in, const int* in_sizes, int n_in,
                              void* d_out, int out_size, void* d_ws, size_t ws_size,
                              hipStream_t stream) {
    (void)d_ws; (void)ws_size; (void)in_sizes; (void)n_in;
    const float* v_re  = (const float*)d_in[0];
    const float* v_im  = (const float*)d_in[1];
    const float* W2_re = (const float*)d_in[2];
    const float* W2_im = (const float*)d_in[3];
    const float* x_re  = (const float*)d_in[4];
    const float* x_im  = (const float*)d_in[5];
    const float* y_re  = (const float*)d_in[6];
    const float* y_im  = (const float*)d_in[7];
    float* out = (float*)d_out;

    build_all<<<1537, 256, 0, stream>>>(v_re, v_im, W2_re, W2_im,
                                        x_re, x_im, y_re, y_im);
    fft_conv<<<1024, 128, 0, stream>>>();
    gemm_w2y<<<512, 256, 0, stream>>>(out, out_size);
}